// Round 15
// baseline (398.027 us; speedup 1.0000x reference)
//
#include <hip/hip_runtime.h>
#include <float.h>
#include <math.h>

// Problem constants (fixed by the reference)
constexpr int Cc = 19;    // classes
constexpr int Kk = 50;    // pca dim
constexpr int Dd = 256;   // feature dim

constexpr int NCOL = 64;          // padded cols per class (50 -> 64)
constexpr int CPAD = 20;          // classes incl 1 dummy pad class (Bs sizing)
constexpr int ROWS = CPAD * NCOL; // 1280 rows of the stacked B matrix
constexpr int MT   = 128;         // pixels per block (proven best geometry)
constexpr int THR  = 512;         // 8 waves

typedef float  f32x4  __attribute__((ext_vector_type(4)));
typedef short  bf16x8 __attribute__((ext_vector_type(8)));

__device__ __forceinline__ unsigned short f2bf(float x) {
  unsigned u = __float_as_uint(x);
  unsigned r = 0x7FFFu + ((u >> 16) & 1u);   // round-to-nearest-even
  return (unsigned short)((u + r) >> 16);
}
__device__ __forceinline__ float bf2f(unsigned short h) {
  return __uint_as_float(((unsigned)h) << 16);
}

// ---------------------------------------------------------------------------
// Prep 1+2 fused (19 blocks x 64 thr — fusion does not collapse parallelism):
// rv = 1/sqrt(var); bc = mean_proj*rv + mu (LDS); Cholesky cov_inv = L L^T
// in LDS; store Lmat and g = L^T bc (0-padded).
// ---------------------------------------------------------------------------
__global__ void prepchol_kernel(const float* __restrict__ pca_mean,
                                const float* __restrict__ comps,
                                const float* __restrict__ var,
                                const float* __restrict__ mu,
                                const float* __restrict__ cov_inv,
                                float* __restrict__ w_rv,
                                float* __restrict__ Lmat,
                                float* __restrict__ g) {
  __shared__ float M[Kk * Kk];
  __shared__ float bcs[Kk];
  const int c = blockIdx.x, t = threadIdx.x;

  if (t < Kk) {
    const float* m  = pca_mean + (size_t)c * Dd;
    const float* cp = comps + ((size_t)(c * Kk + t)) * Dd;
    float s = 0.f;
    #pragma unroll 8
    for (int d = 0; d < Dd; ++d) s = fmaf(m[d], cp[d], s);
    float rv = 1.0f / sqrtf(var[c * Kk + t]);
    w_rv[c * Kk + t] = rv;
    bcs[t] = fmaf(s, rv, mu[c * Kk + t]);
  }
  for (int i = t; i < Kk * Kk; i += 64) M[i] = cov_inv[(size_t)c * Kk * Kk + i];
  __syncthreads();
  for (int j = 0; j < Kk; ++j) {
    if (t == 0) M[j * Kk + j] = sqrtf(M[j * Kk + j]);
    __syncthreads();
    float dj = M[j * Kk + j];
    for (int i = j + 1 + t; i < Kk; i += 64) M[i * Kk + j] /= dj;
    __syncthreads();
    for (int i = j + 1 + t; i < Kk; i += 64) {
      float mij = M[i * Kk + j];
      for (int l = j + 1; l <= i; ++l) M[i * Kk + l] -= mij * M[l * Kk + j];
    }
    __syncthreads();
  }
  for (int i = t; i < Kk * Kk; i += 64) Lmat[(size_t)c * Kk * Kk + i] = M[i];
  float s = 0.f;
  if (t < Kk) {
    for (int k = t; k < Kk; ++k) s = fmaf(M[k * Kk + t], bcs[k], s);
  }
  if (t < NCOL) g[c * NCOL + t] = s;
}

// ---------------------------------------------------------------------------
// Prep 3: B in FRAGMENT-ORDER global layout, split-bf16, 1280 blocks (one
// per padded row — whole chip participates; Round-10 lesson).
// B[c][j][d] = sum_{k>=j} L[k][j]*rv[k]*comps[c][k][d]; hi chunks 0..7,
// residual lo chunks 8..15; chunk = [col 0..63][kq 0..3][8 bf16] = 4096 B.
// Pad class c==19: B=0, g=1e18 (mfma skips it anyway).
// ---------------------------------------------------------------------------
__global__ void prepB_kernel(const float* __restrict__ comps,
                             const float* __restrict__ w_rv,
                             const float* __restrict__ Lmat,
                             float* __restrict__ g,
                             unsigned short* __restrict__ Bs) {
  const int r = blockIdx.x;          // 0..1279
  const int c = r >> 6, j = r & 63;
  const int d = threadIdx.x;         // 0..255
  const unsigned hi_idx =
      (unsigned)(c * 16 + (d >> 5)) * 2048u + (unsigned)j * 32u + (unsigned)(d & 31);
  const unsigned lo_idx = hi_idx + 8u * 2048u;   // chunks 8..15
  if (c >= Cc || j >= Kk) {
    Bs[hi_idx] = 0; Bs[lo_idx] = 0;
    if (c >= Cc && d == 0) g[r] = 1e18f;
    return;
  }
  float s = 0.f;
  for (int k = j; k < Kk; ++k)
    s = fmaf(Lmat[(size_t)c * Kk * Kk + k * Kk + j] * w_rv[c * Kk + k],
             comps[((size_t)c * Kk + k) * Dd + d], s);
  unsigned short hi = f2bf(s);
  Bs[hi_idx] = hi;
  Bs[lo_idx] = f2bf(s - bf2f(hi));
}

// ---------------------------------------------------------------------------
// Main: split-bf16 MFMA GEMM, B register-streamed from L2, A frags
// register-pipelined one chunk ahead.
//
// Round-15 change (numerically identical, order-only): MERGE the two
// phases. Old: phase A = 8 chunks x 32 MFMA (aH,aL x B_hi), phase B =
// 8 chunks x 16 MFMA (aH x B_lo) — phase B's 77cy MFMA runs can't hide
// its load batch, dragging MfmaUtil to 42%. New: per chunk t process
// B_hi[t] AND B_lo[t] together: prefetch 8 B frags + 8 A frags for t+1,
// then 48 MFMA (~230cy) from last chunk's regs. 8 chunks/class, longer
// runs, half the loop overhead. Register demand ~230 <= 256 budget at
// 2 waves/SIMD (waves_per_eu(2,2)); sched_barrier(0) per chunk keeps the
// scheduler from hoisting loads >1 chunk ahead (Round-8 spill mode).
// ---------------------------------------------------------------------------
__global__ __launch_bounds__(THR)
__attribute__((amdgpu_waves_per_eu(2, 2)))
void mfma_kernel(const float* __restrict__ feats,
                 const unsigned short* __restrict__ Bs,
                 const float* __restrict__ g,
                 float* __restrict__ out) {
  __shared__ unsigned short sA[MT * 512];   // 131072 B, xor-swizzled
  __shared__ unsigned sMin[MT];

  const int tid  = threadIdx.x;
  const int lane = tid & 63;
  const int wid  = tid >> 6;
  const int mh   = wid >> 2;                // 0..1 : rows [mh*64, +64)
  const int slot = wid & 3;                 // class-slot
  const int l15  = lane & 15;
  const int lk   = (lane >> 4) * 8;         // k-quarter offset (elems)
  const size_t pxbase = (size_t)blockIdx.x * MT;

  if (tid < MT) sMin[tid] = 0x7F7FFFFFu;    // FLT_MAX bits

  // ---- Stage A: fp32 feats -> bf16 hi (elems 0..255) | lo (256..511)
  {
    const int px = tid >> 2;
    const int db = (tid & 3) * 64;
    const float4* src = (const float4*)(feats + (pxbase + px) * Dd + db);
    char* base = (char*)sA;
    #pragma unroll 4
    for (int i = 0; i < 16; ++i) {
      float4 f = src[i];
      int k = db + i * 4;
      unsigned short h0 = f2bf(f.x), h1 = f2bf(f.y), h2 = f2bf(f.z), h3 = f2bf(f.w);
      unsigned short l0 = f2bf(f.x - bf2f(h0)), l1 = f2bf(f.y - bf2f(h1));
      unsigned short l2 = f2bf(f.z - bf2f(h2)), l3 = f2bf(f.w - bf2f(h3));
      uint2 hv, lv;
      hv.x = (unsigned)h0 | ((unsigned)h1 << 16); hv.y = (unsigned)h2 | ((unsigned)h3 << 16);
      lv.x = (unsigned)l0 | ((unsigned)l1 << 16); lv.y = (unsigned)l2 | ((unsigned)l3 << 16);
      unsigned hadr = (unsigned)(px * 1024 + k * 2)         ^ ((px & 7) << 4);
      unsigned ladr = (unsigned)(px * 1024 + (256 + k) * 2) ^ ((px & 7) << 4);
      *(uint2*)(base + hadr) = hv;
      *(uint2*)(base + ladr) = lv;
    }
  }
  __syncthreads();

  // A-frag address components (XOR swizzle applied after row-base + k sum)
  unsigned rowb[4], swr[4];
  #pragma unroll
  for (int mf = 0; mf < 4; ++mf) {
    int row = mh * 64 + mf * 16 + l15;
    rowb[mf] = (unsigned)(row * 1024);
    swr[mf]  = (unsigned)((row & 7) << 4);
  }
  const char* sAc = (const char*)sA;
  const unsigned lk2 = (unsigned)(lk * 2);  // byte offset of kh(0)

  float dmin[4][4];
  #pragma unroll
  for (int mf = 0; mf < 4; ++mf)
    #pragma unroll
    for (int r = 0; r < 4; ++r) dmin[mf][r] = FLT_MAX;

  const unsigned be = (unsigned)(l15 * 32 + lk);   // shorts, within 16-col grp

  #pragma unroll 1
  for (int ci = 0; ci < CPAD / 4; ++ci) {
    const int cl = ci * 4 + slot;
    if (cl >= Cc) continue;                 // wave-uniform dummy-class skip
    const unsigned short* Bb = Bs + (size_t)cl * (16 * 2048);

    float gv[4];
    #pragma unroll
    for (int nf = 0; nf < 4; ++nf) gv[nf] = g[cl * NCOL + nf * 16 + l15];

    f32x4 acc[4][4];
    #pragma unroll
    for (int mf = 0; mf < 4; ++mf)
      #pragma unroll
      for (int nf = 0; nf < 4; ++nf) acc[mf][nf] = (f32x4)0.f;

    // ---- prologue: chunk 0's B_hi + B_lo + A_hi + A_lo into current regs
    bf16x8 bh0 = *(const bf16x8*)(Bb + 0 * 512 + be);
    bf16x8 bh1 = *(const bf16x8*)(Bb + 1 * 512 + be);
    bf16x8 bh2 = *(const bf16x8*)(Bb + 2 * 512 + be);
    bf16x8 bh3 = *(const bf16x8*)(Bb + 3 * 512 + be);
    bf16x8 bl0 = *(const bf16x8*)(Bb + 8 * 2048 + 0 * 512 + be);
    bf16x8 bl1 = *(const bf16x8*)(Bb + 8 * 2048 + 1 * 512 + be);
    bf16x8 bl2 = *(const bf16x8*)(Bb + 8 * 2048 + 2 * 512 + be);
    bf16x8 bl3 = *(const bf16x8*)(Bb + 8 * 2048 + 3 * 512 + be);
    bf16x8 cH[4], cL[4];
    #pragma unroll
    for (int mf = 0; mf < 4; ++mf)
      cH[mf] = *(const bf16x8*)(sAc + ((rowb[mf] + lk2) ^ swr[mf]));
    #pragma unroll
    for (int mf = 0; mf < 4; ++mf)
      cL[mf] = *(const bf16x8*)(sAc + ((rowb[mf] + lk2 + 512) ^ swr[mf]));

    // ---- merged loop: 8 chunks, 48 MFMA each (aH*bh, aL*bh, aH*bl)
    #pragma unroll
    for (int tb = 0; tb < 8; ++tb) {
      bf16x8 nh0, nh1, nh2, nh3, nl0, nl1, nl2, nl3, nH[4], nL[4];
      if (tb < 7) {
        nh0 = *(const bf16x8*)(Bb + (tb + 1) * 2048 + 0 * 512 + be);
        nh1 = *(const bf16x8*)(Bb + (tb + 1) * 2048 + 1 * 512 + be);
        nh2 = *(const bf16x8*)(Bb + (tb + 1) * 2048 + 2 * 512 + be);
        nh3 = *(const bf16x8*)(Bb + (tb + 1) * 2048 + 3 * 512 + be);
        nl0 = *(const bf16x8*)(Bb + (9 + tb) * 2048 + 0 * 512 + be);
        nl1 = *(const bf16x8*)(Bb + (9 + tb) * 2048 + 1 * 512 + be);
        nl2 = *(const bf16x8*)(Bb + (9 + tb) * 2048 + 2 * 512 + be);
        nl3 = *(const bf16x8*)(Bb + (9 + tb) * 2048 + 3 * 512 + be);
        const unsigned nkh = (unsigned)((tb + 1) * 64) + lk2;
        #pragma unroll
        for (int mf = 0; mf < 4; ++mf)
          nH[mf] = *(const bf16x8*)(sAc + ((rowb[mf] + nkh) ^ swr[mf]));
        #pragma unroll
        for (int mf = 0; mf < 4; ++mf)
          nL[mf] = *(const bf16x8*)(sAc + ((rowb[mf] + nkh + 512) ^ swr[mf]));
      }
      // compute current chunk from last chunk's regs: 48 MFMA
      __builtin_amdgcn_s_setprio(1);
      #pragma unroll
      for (int mf = 0; mf < 4; ++mf) {
        acc[mf][0] = __builtin_amdgcn_mfma_f32_16x16x32_bf16(cH[mf], bh0, acc[mf][0], 0, 0, 0);
        acc[mf][1] = __builtin_amdgcn_mfma_f32_16x16x32_bf16(cH[mf], bh1, acc[mf][1], 0, 0, 0);
        acc[mf][2] = __builtin_amdgcn_mfma_f32_16x16x32_bf16(cH[mf], bh2, acc[mf][2], 0, 0, 0);
        acc[mf][3] = __builtin_amdgcn_mfma_f32_16x16x32_bf16(cH[mf], bh3, acc[mf][3], 0, 0, 0);
      }
      #pragma unroll
      for (int mf = 0; mf < 4; ++mf) {
        acc[mf][0] = __builtin_amdgcn_mfma_f32_16x16x32_bf16(cL[mf], bh0, acc[mf][0], 0, 0, 0);
        acc[mf][1] = __builtin_amdgcn_mfma_f32_16x16x32_bf16(cL[mf], bh1, acc[mf][1], 0, 0, 0);
        acc[mf][2] = __builtin_amdgcn_mfma_f32_16x16x32_bf16(cL[mf], bh2, acc[mf][2], 0, 0, 0);
        acc[mf][3] = __builtin_amdgcn_mfma_f32_16x16x32_bf16(cL[mf], bh3, acc[mf][3], 0, 0, 0);
      }
      #pragma unroll
      for (int mf = 0; mf < 4; ++mf) {
        acc[mf][0] = __builtin_amdgcn_mfma_f32_16x16x32_bf16(cH[mf], bl0, acc[mf][0], 0, 0, 0);
        acc[mf][1] = __builtin_amdgcn_mfma_f32_16x16x32_bf16(cH[mf], bl1, acc[mf][1], 0, 0, 0);
        acc[mf][2] = __builtin_amdgcn_mfma_f32_16x16x32_bf16(cH[mf], bl2, acc[mf][2], 0, 0, 0);
        acc[mf][3] = __builtin_amdgcn_mfma_f32_16x16x32_bf16(cH[mf], bl3, acc[mf][3], 0, 0, 0);
      }
      __builtin_amdgcn_s_setprio(0);
      // rotate pipeline regs
      if (tb < 7) {
        #pragma unroll
        for (int mf = 0; mf < 4; ++mf) { cH[mf] = nH[mf]; cL[mf] = nL[mf]; }
        bh0 = nh0; bh1 = nh1; bh2 = nh2; bh3 = nh3;
        bl0 = nl0; bl1 = nl1; bl2 = nl2; bl3 = nl3;
      }
      __builtin_amdgcn_sched_barrier(0);   // hold loads to exactly 1 chunk ahead
    }

    // ---- epilogue: complete dist for this class, per row; running min
    #pragma unroll
    for (int mf = 0; mf < 4; ++mf) {
      float ps0 = 0.f, ps1 = 0.f, ps2 = 0.f, ps3 = 0.f;
      #pragma unroll
      for (int nf = 0; nf < 4; ++nf) {
        float gg = gv[nf];
        float t0 = acc[mf][nf][0] - gg; ps0 = fmaf(t0, t0, ps0);
        float t1 = acc[mf][nf][1] - gg; ps1 = fmaf(t1, t1, ps1);
        float t2 = acc[mf][nf][2] - gg; ps2 = fmaf(t2, t2, ps2);
        float t3 = acc[mf][nf][3] - gg; ps3 = fmaf(t3, t3, ps3);
      }
      #pragma unroll
      for (int off = 1; off < 16; off <<= 1) {
        ps0 += __shfl_xor(ps0, off);
        ps1 += __shfl_xor(ps1, off);
        ps2 += __shfl_xor(ps2, off);
        ps3 += __shfl_xor(ps3, off);
      }
      dmin[mf][0] = fminf(dmin[mf][0], ps0);
      dmin[mf][1] = fminf(dmin[mf][1], ps1);
      dmin[mf][2] = fminf(dmin[mf][2], ps2);
      dmin[mf][3] = fminf(dmin[mf][3], ps3);
    }
  }

  // ---- combine the 4 class-slot waves per row-half
  if (l15 == 0) {
    #pragma unroll
    for (int mf = 0; mf < 4; ++mf)
      #pragma unroll
      for (int r = 0; r < 4; ++r) {
        int row = mh * 64 + mf * 16 + (lane >> 4) * 4 + r;
        atomicMin(&sMin[row], __float_as_uint(dmin[mf][r]));
      }
  }
  __syncthreads();
  if (tid < MT) out[pxbase + tid] = __uint_as_float(sMin[tid]);
}

extern "C" void kernel_launch(void* const* d_in, const int* in_sizes, int n_in,
                              void* d_out, int out_size, void* d_ws, size_t ws_size,
                              hipStream_t stream) {
  const float* feats    = (const float*)d_in[0];
  const float* pca_mean = (const float*)d_in[1];
  const float* comps    = (const float*)d_in[2];
  const float* var      = (const float*)d_in[3];
  const float* mu       = (const float*)d_in[4];
  const float* cov_inv  = (const float*)d_in[5];
  float* out = (float*)d_out;

  // workspace (floats): rv[950] Lmat[47500] g[1280] Bs(bf16)[655360]
  float* w_rv = (float*)d_ws;
  float* Lmat = w_rv + Cc * Kk;
  float* gv   = Lmat + Cc * Kk * Kk;
  unsigned short* Bs = (unsigned short*)(gv + ROWS);

  const int n = in_sizes[0] / Dd;  // 131072 pixels

  prepchol_kernel<<<Cc, 64, 0, stream>>>(pca_mean, comps, var, mu, cov_inv,
                                         w_rv, Lmat, gv);
  prepB_kernel<<<ROWS, 256, 0, stream>>>(comps, w_rv, Lmat, gv, Bs);
  mfma_kernel<<<n / MT, THR, 0, stream>>>(feats, Bs, gv, out);
}

// Round 16
// 284.041 us; speedup vs baseline: 1.4013x; 1.4013x over previous
//
#include <hip/hip_runtime.h>
#include <float.h>
#include <math.h>

// Problem constants (fixed by the reference)
constexpr int Cc = 19;    // classes
constexpr int Kk = 50;    // pca dim
constexpr int Dd = 256;   // feature dim

constexpr int NCOL = 64;          // padded cols per class (50 -> 64)
constexpr int CPAD = 20;          // classes incl 1 dummy pad class (Bs sizing)
constexpr int ROWS = CPAD * NCOL; // 1280 rows of the stacked B matrix
constexpr int MT   = 128;         // pixels per block (proven best geometry)
constexpr int THR  = 512;         // 8 waves

typedef float  f32x4  __attribute__((ext_vector_type(4)));
typedef short  bf16x8 __attribute__((ext_vector_type(8)));

__device__ __forceinline__ unsigned short f2bf(float x) {
  unsigned u = __float_as_uint(x);
  unsigned r = 0x7FFFu + ((u >> 16) & 1u);   // round-to-nearest-even
  return (unsigned short)((u + r) >> 16);
}
__device__ __forceinline__ float bf2f(unsigned short h) {
  return __uint_as_float(((unsigned)h) << 16);
}

// ---------------------------------------------------------------------------
// Prep 1+2 fused: rv = 1/sqrt(var); bc = mean_proj*rv + mu (LDS); Cholesky
// cov_inv = L L^T in LDS; store Lmat and g = L^T bc (0-padded).
//
// Round-16 change: 256 threads + ELEMENT-parallel trailing update. The old
// row-serial update (thread i runs up to 49 serial LDS-FMAs per j-step) was
// ~31us; spreading the (Kk-j-1)^2 elements flat across 256 threads makes
// each j-step ~10 independent ops/thread (~12us total). Writes touch only
// columns >= j+1, reads only column j (untouched this step) -> race-free.
// ---------------------------------------------------------------------------
__global__ __launch_bounds__(256) void prepchol_kernel(
    const float* __restrict__ pca_mean,
    const float* __restrict__ comps,
    const float* __restrict__ var,
    const float* __restrict__ mu,
    const float* __restrict__ cov_inv,
    float* __restrict__ w_rv,
    float* __restrict__ Lmat,
    float* __restrict__ g) {
  __shared__ float M[Kk * Kk];
  __shared__ float bcs[Kk];
  const int c = blockIdx.x, t = threadIdx.x;

  if (t < Kk) {
    const float* m  = pca_mean + (size_t)c * Dd;
    const float* cp = comps + ((size_t)(c * Kk + t)) * Dd;
    float s = 0.f;
    #pragma unroll 8
    for (int d = 0; d < Dd; ++d) s = fmaf(m[d], cp[d], s);
    float rv = 1.0f / sqrtf(var[c * Kk + t]);
    w_rv[c * Kk + t] = rv;
    bcs[t] = fmaf(s, rv, mu[c * Kk + t]);
  }
  for (int i = t; i < Kk * Kk; i += 256) M[i] = cov_inv[(size_t)c * Kk * Kk + i];
  __syncthreads();
  for (int j = 0; j < Kk; ++j) {
    if (t == 0) M[j * Kk + j] = sqrtf(M[j * Kk + j]);
    __syncthreads();
    float dj = M[j * Kk + j];
    for (int i = j + 1 + t; i < Kk; i += 256) M[i * Kk + j] /= dj;
    __syncthreads();
    const int rem = Kk - 1 - j;            // rows/cols j+1 .. Kk-1
    for (int idx = t; idx < rem * rem; idx += 256) {
      const int i = j + 1 + idx / rem;
      const int l = j + 1 + idx % rem;
      if (l <= i) M[i * Kk + l] -= M[i * Kk + j] * M[l * Kk + j];
    }
    __syncthreads();
  }
  for (int i = t; i < Kk * Kk; i += 256) Lmat[(size_t)c * Kk * Kk + i] = M[i];
  float s = 0.f;
  if (t < Kk) {
    for (int k = t; k < Kk; ++k) s = fmaf(M[k * Kk + t], bcs[k], s);
  }
  if (t < NCOL) g[c * NCOL + t] = s;
}

// ---------------------------------------------------------------------------
// Prep 3: B in FRAGMENT-ORDER global layout, split-bf16, 1280 blocks (one
// per padded row — whole chip participates; Round-10 lesson).
// B[c][j][d] = sum_{k>=j} L[k][j]*rv[k]*comps[c][k][d]; hi chunks 0..7,
// residual lo chunks 8..15; chunk = [col 0..63][kq 0..3][8 bf16] = 4096 B.
// Pad class c==19: B=0, g=1e18 (mfma skips it anyway).
// ---------------------------------------------------------------------------
__global__ void prepB_kernel(const float* __restrict__ comps,
                             const float* __restrict__ w_rv,
                             const float* __restrict__ Lmat,
                             float* __restrict__ g,
                             unsigned short* __restrict__ Bs) {
  const int r = blockIdx.x;          // 0..1279
  const int c = r >> 6, j = r & 63;
  const int d = threadIdx.x;         // 0..255
  const unsigned hi_idx =
      (unsigned)(c * 16 + (d >> 5)) * 2048u + (unsigned)j * 32u + (unsigned)(d & 31);
  const unsigned lo_idx = hi_idx + 8u * 2048u;   // chunks 8..15
  if (c >= Cc || j >= Kk) {
    Bs[hi_idx] = 0; Bs[lo_idx] = 0;
    if (c >= Cc && d == 0) g[r] = 1e18f;
    return;
  }
  float s = 0.f;
  for (int k = j; k < Kk; ++k)
    s = fmaf(Lmat[(size_t)c * Kk * Kk + k * Kk + j] * w_rv[c * Kk + k],
             comps[((size_t)c * Kk + k) * Dd + d], s);
  unsigned short hi = f2bf(s);
  Bs[hi_idx] = hi;
  Bs[lo_idx] = f2bf(s - bf2f(hi));
}

// ---------------------------------------------------------------------------
// Main: split-bf16 MFMA GEMM — Round-14 kernel VERBATIM (235us / 42%
// MfmaUtil, reproduced across four rounds). B register-streamed from L2,
// nf=4, A frags register-pipelined one chunk ahead.
//
// Closed design facts (R12/R13/R15): the pipeline's load-state must stay
// at ~96 VGPRs (cur+next of {4 B frags, 8 A frags}). Phase-merge (R15) and
// chunk-pairing both need 128 pipeline VGPRs -> allocator spills (WRITE
// 92MB, MfmaUtil 29%). 4 waves/EU spills (R12/R13). This shape is the
// stable operating point: MT=128, 8 waves, mf=4, nf=4, waves_per_eu(2,2).
// ---------------------------------------------------------------------------
__global__ __launch_bounds__(THR)
__attribute__((amdgpu_waves_per_eu(2, 2)))
void mfma_kernel(const float* __restrict__ feats,
                 const unsigned short* __restrict__ Bs,
                 const float* __restrict__ g,
                 float* __restrict__ out) {
  __shared__ unsigned short sA[MT * 512];   // 131072 B, xor-swizzled
  __shared__ unsigned sMin[MT];

  const int tid  = threadIdx.x;
  const int lane = tid & 63;
  const int wid  = tid >> 6;
  const int mh   = wid >> 2;                // 0..1 : rows [mh*64, +64)
  const int slot = wid & 3;                 // class-slot
  const int l15  = lane & 15;
  const int lk   = (lane >> 4) * 8;         // k-quarter offset (elems)
  const size_t pxbase = (size_t)blockIdx.x * MT;

  if (tid < MT) sMin[tid] = 0x7F7FFFFFu;    // FLT_MAX bits

  // ---- Stage A: fp32 feats -> bf16 hi (elems 0..255) | lo (256..511)
  {
    const int px = tid >> 2;
    const int db = (tid & 3) * 64;
    const float4* src = (const float4*)(feats + (pxbase + px) * Dd + db);
    char* base = (char*)sA;
    #pragma unroll 4
    for (int i = 0; i < 16; ++i) {
      float4 f = src[i];
      int k = db + i * 4;
      unsigned short h0 = f2bf(f.x), h1 = f2bf(f.y), h2 = f2bf(f.z), h3 = f2bf(f.w);
      unsigned short l0 = f2bf(f.x - bf2f(h0)), l1 = f2bf(f.y - bf2f(h1));
      unsigned short l2 = f2bf(f.z - bf2f(h2)), l3 = f2bf(f.w - bf2f(h3));
      uint2 hv, lv;
      hv.x = (unsigned)h0 | ((unsigned)h1 << 16); hv.y = (unsigned)h2 | ((unsigned)h3 << 16);
      lv.x = (unsigned)l0 | ((unsigned)l1 << 16); lv.y = (unsigned)l2 | ((unsigned)l3 << 16);
      unsigned hadr = (unsigned)(px * 1024 + k * 2)         ^ ((px & 7) << 4);
      unsigned ladr = (unsigned)(px * 1024 + (256 + k) * 2) ^ ((px & 7) << 4);
      *(uint2*)(base + hadr) = hv;
      *(uint2*)(base + ladr) = lv;
    }
  }
  __syncthreads();

  // A-frag address components (XOR swizzle applied after row-base + k sum)
  unsigned rowb[4], swr[4];
  #pragma unroll
  for (int mf = 0; mf < 4; ++mf) {
    int row = mh * 64 + mf * 16 + l15;
    rowb[mf] = (unsigned)(row * 1024);
    swr[mf]  = (unsigned)((row & 7) << 4);
  }
  const char* sAc = (const char*)sA;
  const unsigned lk2 = (unsigned)(lk * 2);  // byte offset of kh(0)

  float dmin[4][4];
  #pragma unroll
  for (int mf = 0; mf < 4; ++mf)
    #pragma unroll
    for (int r = 0; r < 4; ++r) dmin[mf][r] = FLT_MAX;

  const unsigned be = (unsigned)(l15 * 32 + lk);   // shorts, within 16-col grp

  #pragma unroll 1
  for (int ci = 0; ci < CPAD / 4; ++ci) {
    const int cl = ci * 4 + slot;
    if (cl >= Cc) continue;                 // wave-uniform dummy-class skip
    const unsigned short* Bb = Bs + (size_t)cl * (16 * 2048);

    float gv[4];
    #pragma unroll
    for (int nf = 0; nf < 4; ++nf) gv[nf] = g[cl * NCOL + nf * 16 + l15];

    f32x4 acc[4][4];
    #pragma unroll
    for (int mf = 0; mf < 4; ++mf)
      #pragma unroll
      for (int nf = 0; nf < 4; ++nf) acc[mf][nf] = (f32x4)0.f;

    // ---- prologue: B chunk 0 + A chunk 0 (kh & kl) into current regs
    bf16x8 b0 = *(const bf16x8*)(Bb + 0 * 512 + be);
    bf16x8 b1 = *(const bf16x8*)(Bb + 1 * 512 + be);
    bf16x8 b2 = *(const bf16x8*)(Bb + 2 * 512 + be);
    bf16x8 b3 = *(const bf16x8*)(Bb + 3 * 512 + be);
    bf16x8 cH[4], cL[4];
    #pragma unroll
    for (int mf = 0; mf < 4; ++mf)
      cH[mf] = *(const bf16x8*)(sAc + ((rowb[mf] + lk2) ^ swr[mf]));
    #pragma unroll
    for (int mf = 0; mf < 4; ++mf)
      cL[mf] = *(const bf16x8*)(sAc + ((rowb[mf] + lk2 + 512) ^ swr[mf]));

    // ---- phase A: B_hi chunks 0..7, A_hi + A_lo; loads pipelined 1 ahead
    #pragma unroll
    for (int tb = 0; tb < 8; ++tb) {
      // issue next-chunk loads FIRST (B then A); tb==7 feeds phase B
      bf16x8 n0 = *(const bf16x8*)(Bb + (tb + 1) * 2048 + 0 * 512 + be);
      bf16x8 n1 = *(const bf16x8*)(Bb + (tb + 1) * 2048 + 1 * 512 + be);
      bf16x8 n2 = *(const bf16x8*)(Bb + (tb + 1) * 2048 + 2 * 512 + be);
      bf16x8 n3 = *(const bf16x8*)(Bb + (tb + 1) * 2048 + 3 * 512 + be);
      const unsigned nkh = (unsigned)((((tb + 1) & 7) * 64) + lk2);
      bf16x8 nH[4], nL[4];
      #pragma unroll
      for (int mf = 0; mf < 4; ++mf)
        nH[mf] = *(const bf16x8*)(sAc + ((rowb[mf] + nkh) ^ swr[mf]));
      if (tb < 7) {
        #pragma unroll
        for (int mf = 0; mf < 4; ++mf)
          nL[mf] = *(const bf16x8*)(sAc + ((rowb[mf] + nkh + 512) ^ swr[mf]));
      }
      // compute current chunk from last chunk's regs
      __builtin_amdgcn_s_setprio(1);
      #pragma unroll
      for (int mf = 0; mf < 4; ++mf) {
        acc[mf][0] = __builtin_amdgcn_mfma_f32_16x16x32_bf16(cH[mf], b0, acc[mf][0], 0, 0, 0);
        acc[mf][1] = __builtin_amdgcn_mfma_f32_16x16x32_bf16(cH[mf], b1, acc[mf][1], 0, 0, 0);
        acc[mf][2] = __builtin_amdgcn_mfma_f32_16x16x32_bf16(cH[mf], b2, acc[mf][2], 0, 0, 0);
        acc[mf][3] = __builtin_amdgcn_mfma_f32_16x16x32_bf16(cH[mf], b3, acc[mf][3], 0, 0, 0);
      }
      #pragma unroll
      for (int mf = 0; mf < 4; ++mf) {
        acc[mf][0] = __builtin_amdgcn_mfma_f32_16x16x32_bf16(cL[mf], b0, acc[mf][0], 0, 0, 0);
        acc[mf][1] = __builtin_amdgcn_mfma_f32_16x16x32_bf16(cL[mf], b1, acc[mf][1], 0, 0, 0);
        acc[mf][2] = __builtin_amdgcn_mfma_f32_16x16x32_bf16(cL[mf], b2, acc[mf][2], 0, 0, 0);
        acc[mf][3] = __builtin_amdgcn_mfma_f32_16x16x32_bf16(cL[mf], b3, acc[mf][3], 0, 0, 0);
      }
      __builtin_amdgcn_s_setprio(0);
      // rotate pipeline regs
      #pragma unroll
      for (int mf = 0; mf < 4; ++mf) {
        cH[mf] = nH[mf];
        if (tb < 7) cL[mf] = nL[mf];
      }
      b0 = n0; b1 = n1; b2 = n2; b3 = n3;
      __builtin_amdgcn_sched_barrier(0);   // hold loads to exactly 1 chunk ahead
    }

    // ---- phase B: B_lo chunks 8..15, A_hi only; same pipeline
    #pragma unroll
    for (int tb = 0; tb < 8; ++tb) {
      bf16x8 n0, n1, n2, n3, nH[4];
      if (tb < 7) {
        n0 = *(const bf16x8*)(Bb + (9 + tb) * 2048 + 0 * 512 + be);
        n1 = *(const bf16x8*)(Bb + (9 + tb) * 2048 + 1 * 512 + be);
        n2 = *(const bf16x8*)(Bb + (9 + tb) * 2048 + 2 * 512 + be);
        n3 = *(const bf16x8*)(Bb + (9 + tb) * 2048 + 3 * 512 + be);
        const unsigned nkh = (unsigned)(((tb + 1) * 64) + lk2);
        #pragma unroll
        for (int mf = 0; mf < 4; ++mf)
          nH[mf] = *(const bf16x8*)(sAc + ((rowb[mf] + nkh) ^ swr[mf]));
      }
      __builtin_amdgcn_s_setprio(1);
      #pragma unroll
      for (int mf = 0; mf < 4; ++mf) {
        acc[mf][0] = __builtin_amdgcn_mfma_f32_16x16x32_bf16(cH[mf], b0, acc[mf][0], 0, 0, 0);
        acc[mf][1] = __builtin_amdgcn_mfma_f32_16x16x32_bf16(cH[mf], b1, acc[mf][1], 0, 0, 0);
        acc[mf][2] = __builtin_amdgcn_mfma_f32_16x16x32_bf16(cH[mf], b2, acc[mf][2], 0, 0, 0);
        acc[mf][3] = __builtin_amdgcn_mfma_f32_16x16x32_bf16(cH[mf], b3, acc[mf][3], 0, 0, 0);
      }
      __builtin_amdgcn_s_setprio(0);
      if (tb < 7) {
        #pragma unroll
        for (int mf = 0; mf < 4; ++mf) cH[mf] = nH[mf];
        b0 = n0; b1 = n1; b2 = n2; b3 = n3;
      }
      __builtin_amdgcn_sched_barrier(0);
    }

    // ---- epilogue: complete dist for this class, per row; running min
    #pragma unroll
    for (int mf = 0; mf < 4; ++mf) {
      float ps0 = 0.f, ps1 = 0.f, ps2 = 0.f, ps3 = 0.f;
      #pragma unroll
      for (int nf = 0; nf < 4; ++nf) {
        float gg = gv[nf];
        float t0 = acc[mf][nf][0] - gg; ps0 = fmaf(t0, t0, ps0);
        float t1 = acc[mf][nf][1] - gg; ps1 = fmaf(t1, t1, ps1);
        float t2 = acc[mf][nf][2] - gg; ps2 = fmaf(t2, t2, ps2);
        float t3 = acc[mf][nf][3] - gg; ps3 = fmaf(t3, t3, ps3);
      }
      #pragma unroll
      for (int off = 1; off < 16; off <<= 1) {
        ps0 += __shfl_xor(ps0, off);
        ps1 += __shfl_xor(ps1, off);
        ps2 += __shfl_xor(ps2, off);
        ps3 += __shfl_xor(ps3, off);
      }
      dmin[mf][0] = fminf(dmin[mf][0], ps0);
      dmin[mf][1] = fminf(dmin[mf][1], ps1);
      dmin[mf][2] = fminf(dmin[mf][2], ps2);
      dmin[mf][3] = fminf(dmin[mf][3], ps3);
    }
  }

  // ---- combine the 4 class-slot waves per row-half
  if (l15 == 0) {
    #pragma unroll
    for (int mf = 0; mf < 4; ++mf)
      #pragma unroll
      for (int r = 0; r < 4; ++r) {
        int row = mh * 64 + mf * 16 + (lane >> 4) * 4 + r;
        atomicMin(&sMin[row], __float_as_uint(dmin[mf][r]));
      }
  }
  __syncthreads();
  if (tid < MT) out[pxbase + tid] = __uint_as_float(sMin[tid]);
}

extern "C" void kernel_launch(void* const* d_in, const int* in_sizes, int n_in,
                              void* d_out, int out_size, void* d_ws, size_t ws_size,
                              hipStream_t stream) {
  const float* feats    = (const float*)d_in[0];
  const float* pca_mean = (const float*)d_in[1];
  const float* comps    = (const float*)d_in[2];
  const float* var      = (const float*)d_in[3];
  const float* mu       = (const float*)d_in[4];
  const float* cov_inv  = (const float*)d_in[5];
  float* out = (float*)d_out;

  // workspace (floats): rv[950] Lmat[47500] g[1280] Bs(bf16)[655360]
  float* w_rv = (float*)d_ws;
  float* Lmat = w_rv + Cc * Kk;
  float* gv   = Lmat + Cc * Kk * Kk;
  unsigned short* Bs = (unsigned short*)(gv + ROWS);

  const int n = in_sizes[0] / Dd;  // 131072 pixels

  prepchol_kernel<<<Cc, 256, 0, stream>>>(pca_mean, comps, var, mu, cov_inv,
                                          w_rv, Lmat, gv);
  prepB_kernel<<<ROWS, 256, 0, stream>>>(comps, w_rv, Lmat, gv, Bs);
  mfma_kernel<<<n / MT, THR, 0, stream>>>(feats, Bs, gv, out);
}

// Round 17
// 268.640 us; speedup vs baseline: 1.4816x; 1.0573x over previous
//
#include <hip/hip_runtime.h>
#include <float.h>
#include <math.h>

// Problem constants (fixed by the reference)
constexpr int Cc = 19;    // classes
constexpr int Kk = 50;    // pca dim
constexpr int Dd = 256;   // feature dim

constexpr int NCOL = 64;          // padded cols per class (50 -> 64)
constexpr int CPAD = 20;          // classes incl 1 dummy pad class (Bs sizing)
constexpr int ROWS = CPAD * NCOL; // 1280 rows of the stacked B matrix
constexpr int MT   = 128;         // pixels per block (proven best geometry)
constexpr int THR  = 512;         // 8 waves

typedef float  f32x4  __attribute__((ext_vector_type(4)));
typedef short  bf16x8 __attribute__((ext_vector_type(8)));

__device__ __forceinline__ unsigned short f2bf(float x) {
  unsigned u = __float_as_uint(x);
  unsigned r = 0x7FFFu + ((u >> 16) & 1u);   // round-to-nearest-even
  return (unsigned short)((u + r) >> 16);
}
__device__ __forceinline__ float bf2f(unsigned short h) {
  return __uint_as_float(((unsigned)h) << 16);
}

// ---------------------------------------------------------------------------
// Prep 1+2 fused: rv = 1/sqrt(var); bc = mean_proj*rv + mu (LDS); Cholesky
// cov_inv = L L^T in LDS (element-parallel trailing update, R16 — saved
// ~30us); store Lmat and g = L^T bc (0-padded).
// ---------------------------------------------------------------------------
__global__ __launch_bounds__(256) void prepchol_kernel(
    const float* __restrict__ pca_mean,
    const float* __restrict__ comps,
    const float* __restrict__ var,
    const float* __restrict__ mu,
    const float* __restrict__ cov_inv,
    float* __restrict__ w_rv,
    float* __restrict__ Lmat,
    float* __restrict__ g) {
  __shared__ float M[Kk * Kk];
  __shared__ float bcs[Kk];
  const int c = blockIdx.x, t = threadIdx.x;

  if (t < Kk) {
    const float* m  = pca_mean + (size_t)c * Dd;
    const float* cp = comps + ((size_t)(c * Kk + t)) * Dd;
    float s = 0.f;
    #pragma unroll 8
    for (int d = 0; d < Dd; ++d) s = fmaf(m[d], cp[d], s);
    float rv = 1.0f / sqrtf(var[c * Kk + t]);
    w_rv[c * Kk + t] = rv;
    bcs[t] = fmaf(s, rv, mu[c * Kk + t]);
  }
  for (int i = t; i < Kk * Kk; i += 256) M[i] = cov_inv[(size_t)c * Kk * Kk + i];
  __syncthreads();
  for (int j = 0; j < Kk; ++j) {
    if (t == 0) M[j * Kk + j] = sqrtf(M[j * Kk + j]);
    __syncthreads();
    float dj = M[j * Kk + j];
    for (int i = j + 1 + t; i < Kk; i += 256) M[i * Kk + j] /= dj;
    __syncthreads();
    const int rem = Kk - 1 - j;            // rows/cols j+1 .. Kk-1
    for (int idx = t; idx < rem * rem; idx += 256) {
      const int i = j + 1 + idx / rem;
      const int l = j + 1 + idx % rem;
      if (l <= i) M[i * Kk + l] -= M[i * Kk + j] * M[l * Kk + j];
    }
    __syncthreads();
  }
  for (int i = t; i < Kk * Kk; i += 256) Lmat[(size_t)c * Kk * Kk + i] = M[i];
  float s = 0.f;
  if (t < Kk) {
    for (int k = t; k < Kk; ++k) s = fmaf(M[k * Kk + t], bcs[k], s);
  }
  if (t < NCOL) g[c * NCOL + t] = s;
}

// ---------------------------------------------------------------------------
// Prep 3: B in FRAGMENT-ORDER global layout, split-bf16, 1280 blocks (one
// per padded row — whole chip participates; Round-10 lesson).
// B[c][j][d] = sum_{k>=j} L[k][j]*rv[k]*comps[c][k][d]; hi chunks 0..7,
// residual lo chunks 8..15; chunk = [col 0..63][kq 0..3][8 bf16] = 4096 B.
// Pad class c==19: B=0, g=1e18 (mfma skips it anyway).
// ---------------------------------------------------------------------------
__global__ void prepB_kernel(const float* __restrict__ comps,
                             const float* __restrict__ w_rv,
                             const float* __restrict__ Lmat,
                             float* __restrict__ g,
                             unsigned short* __restrict__ Bs) {
  const int r = blockIdx.x;          // 0..1279
  const int c = r >> 6, j = r & 63;
  const int d = threadIdx.x;         // 0..255
  const unsigned hi_idx =
      (unsigned)(c * 16 + (d >> 5)) * 2048u + (unsigned)j * 32u + (unsigned)(d & 31);
  const unsigned lo_idx = hi_idx + 8u * 2048u;   // chunks 8..15
  if (c >= Cc || j >= Kk) {
    Bs[hi_idx] = 0; Bs[lo_idx] = 0;
    if (c >= Cc && d == 0) g[r] = 1e18f;
    return;
  }
  float s = 0.f;
  for (int k = j; k < Kk; ++k)
    s = fmaf(Lmat[(size_t)c * Kk * Kk + k * Kk + j] * w_rv[c * Kk + k],
             comps[((size_t)c * Kk + k) * Dd + d], s);
  unsigned short hi = f2bf(s);
  Bs[hi_idx] = hi;
  Bs[lo_idx] = f2bf(s - bf2f(hi));
}

// ---------------------------------------------------------------------------
// Main: split-bf16 MFMA GEMM, B register-streamed from L2.
//
// Round-17 change: trade the A-fragment prefetch for a THIRD wave/SIMD.
// The A double-buffer (nH/nL, 32 VGPR) pushed unified demand to 192 ->
// 2 waves/SIMD. Dropping it (read cH/cL in-chunk; compiler lgkm-waits
// before the first MFMA) cuts demand to ~164 <= 170 = 512/3 budget ->
// waves_per_eu(3,3) admits 3 waves/SIMD. Measured exchange rate: the
// A-prefetch was worth 50us at 2 waves (R9->R10); the third wave adds
// +50% latency coverage on every stall class. B prefetch (the ~250cy
// L2 latency) is kept at 1-chunk depth. sched_barrier(0) per chunk
// still fences the R8 hoist/spill mode.
// ---------------------------------------------------------------------------
__global__ __launch_bounds__(THR)
__attribute__((amdgpu_waves_per_eu(3, 3)))
void mfma_kernel(const float* __restrict__ feats,
                 const unsigned short* __restrict__ Bs,
                 const float* __restrict__ g,
                 float* __restrict__ out) {
  __shared__ unsigned short sA[MT * 512];   // 131072 B, xor-swizzled
  __shared__ unsigned sMin[MT];

  const int tid  = threadIdx.x;
  const int lane = tid & 63;
  const int wid  = tid >> 6;
  const int mh   = wid >> 2;                // 0..1 : rows [mh*64, +64)
  const int slot = wid & 3;                 // class-slot
  const int l15  = lane & 15;
  const int lk   = (lane >> 4) * 8;         // k-quarter offset (elems)
  const size_t pxbase = (size_t)blockIdx.x * MT;

  if (tid < MT) sMin[tid] = 0x7F7FFFFFu;    // FLT_MAX bits

  // ---- Stage A: fp32 feats -> bf16 hi (elems 0..255) | lo (256..511)
  {
    const int px = tid >> 2;
    const int db = (tid & 3) * 64;
    const float4* src = (const float4*)(feats + (pxbase + px) * Dd + db);
    char* base = (char*)sA;
    #pragma unroll 4
    for (int i = 0; i < 16; ++i) {
      float4 f = src[i];
      int k = db + i * 4;
      unsigned short h0 = f2bf(f.x), h1 = f2bf(f.y), h2 = f2bf(f.z), h3 = f2bf(f.w);
      unsigned short l0 = f2bf(f.x - bf2f(h0)), l1 = f2bf(f.y - bf2f(h1));
      unsigned short l2 = f2bf(f.z - bf2f(h2)), l3 = f2bf(f.w - bf2f(h3));
      uint2 hv, lv;
      hv.x = (unsigned)h0 | ((unsigned)h1 << 16); hv.y = (unsigned)h2 | ((unsigned)h3 << 16);
      lv.x = (unsigned)l0 | ((unsigned)l1 << 16); lv.y = (unsigned)l2 | ((unsigned)l3 << 16);
      unsigned hadr = (unsigned)(px * 1024 + k * 2)         ^ ((px & 7) << 4);
      unsigned ladr = (unsigned)(px * 1024 + (256 + k) * 2) ^ ((px & 7) << 4);
      *(uint2*)(base + hadr) = hv;
      *(uint2*)(base + ladr) = lv;
    }
  }
  __syncthreads();

  // A-frag address components (XOR swizzle applied after row-base + k sum)
  unsigned rowb[4], swr[4];
  #pragma unroll
  for (int mf = 0; mf < 4; ++mf) {
    int row = mh * 64 + mf * 16 + l15;
    rowb[mf] = (unsigned)(row * 1024);
    swr[mf]  = (unsigned)((row & 7) << 4);
  }
  const char* sAc = (const char*)sA;
  const unsigned lk2 = (unsigned)(lk * 2);  // byte offset of kh(0)

  float dmin[4][4];
  #pragma unroll
  for (int mf = 0; mf < 4; ++mf)
    #pragma unroll
    for (int r = 0; r < 4; ++r) dmin[mf][r] = FLT_MAX;

  const unsigned be = (unsigned)(l15 * 32 + lk);   // shorts, within 16-col grp

  #pragma unroll 1
  for (int ci = 0; ci < CPAD / 4; ++ci) {
    const int cl = ci * 4 + slot;
    if (cl >= Cc) continue;                 // wave-uniform dummy-class skip
    const unsigned short* Bb = Bs + (size_t)cl * (16 * 2048);

    float gv[4];
    #pragma unroll
    for (int nf = 0; nf < 4; ++nf) gv[nf] = g[cl * NCOL + nf * 16 + l15];

    f32x4 acc[4][4];
    #pragma unroll
    for (int mf = 0; mf < 4; ++mf)
      #pragma unroll
      for (int nf = 0; nf < 4; ++nf) acc[mf][nf] = (f32x4)0.f;

    // ---- prologue: B chunk 0 into current regs (A is read in-chunk)
    bf16x8 b0 = *(const bf16x8*)(Bb + 0 * 512 + be);
    bf16x8 b1 = *(const bf16x8*)(Bb + 1 * 512 + be);
    bf16x8 b2 = *(const bf16x8*)(Bb + 2 * 512 + be);
    bf16x8 b3 = *(const bf16x8*)(Bb + 3 * 512 + be);

    // ---- phase A: B_hi chunks 0..7, A_hi + A_lo read in-chunk
    #pragma unroll
    for (int tb = 0; tb < 8; ++tb) {
      // next-chunk B prefetch (tb==7 feeds phase B chunk 8 = B_lo 0)
      bf16x8 n0 = *(const bf16x8*)(Bb + (tb + 1) * 2048 + 0 * 512 + be);
      bf16x8 n1 = *(const bf16x8*)(Bb + (tb + 1) * 2048 + 1 * 512 + be);
      bf16x8 n2 = *(const bf16x8*)(Bb + (tb + 1) * 2048 + 2 * 512 + be);
      bf16x8 n3 = *(const bf16x8*)(Bb + (tb + 1) * 2048 + 3 * 512 + be);
      const unsigned kh = (unsigned)(tb * 64) + lk2;
      bf16x8 cH[4], cL[4];
      #pragma unroll
      for (int mf = 0; mf < 4; ++mf)
        cH[mf] = *(const bf16x8*)(sAc + ((rowb[mf] + kh) ^ swr[mf]));
      #pragma unroll
      for (int mf = 0; mf < 4; ++mf)
        cL[mf] = *(const bf16x8*)(sAc + ((rowb[mf] + kh + 512) ^ swr[mf]));
      __builtin_amdgcn_s_setprio(1);
      #pragma unroll
      for (int mf = 0; mf < 4; ++mf) {
        acc[mf][0] = __builtin_amdgcn_mfma_f32_16x16x32_bf16(cH[mf], b0, acc[mf][0], 0, 0, 0);
        acc[mf][1] = __builtin_amdgcn_mfma_f32_16x16x32_bf16(cH[mf], b1, acc[mf][1], 0, 0, 0);
        acc[mf][2] = __builtin_amdgcn_mfma_f32_16x16x32_bf16(cH[mf], b2, acc[mf][2], 0, 0, 0);
        acc[mf][3] = __builtin_amdgcn_mfma_f32_16x16x32_bf16(cH[mf], b3, acc[mf][3], 0, 0, 0);
      }
      #pragma unroll
      for (int mf = 0; mf < 4; ++mf) {
        acc[mf][0] = __builtin_amdgcn_mfma_f32_16x16x32_bf16(cL[mf], b0, acc[mf][0], 0, 0, 0);
        acc[mf][1] = __builtin_amdgcn_mfma_f32_16x16x32_bf16(cL[mf], b1, acc[mf][1], 0, 0, 0);
        acc[mf][2] = __builtin_amdgcn_mfma_f32_16x16x32_bf16(cL[mf], b2, acc[mf][2], 0, 0, 0);
        acc[mf][3] = __builtin_amdgcn_mfma_f32_16x16x32_bf16(cL[mf], b3, acc[mf][3], 0, 0, 0);
      }
      __builtin_amdgcn_s_setprio(0);
      b0 = n0; b1 = n1; b2 = n2; b3 = n3;
      __builtin_amdgcn_sched_barrier(0);   // keep loads at 1-chunk depth
    }

    // ---- phase B: B_lo chunks 8..15, A_hi only, read in-chunk
    #pragma unroll
    for (int tb = 0; tb < 8; ++tb) {
      bf16x8 n0, n1, n2, n3;
      if (tb < 7) {
        n0 = *(const bf16x8*)(Bb + (9 + tb) * 2048 + 0 * 512 + be);
        n1 = *(const bf16x8*)(Bb + (9 + tb) * 2048 + 1 * 512 + be);
        n2 = *(const bf16x8*)(Bb + (9 + tb) * 2048 + 2 * 512 + be);
        n3 = *(const bf16x8*)(Bb + (9 + tb) * 2048 + 3 * 512 + be);
      }
      const unsigned kh = (unsigned)(tb * 64) + lk2;
      bf16x8 cH[4];
      #pragma unroll
      for (int mf = 0; mf < 4; ++mf)
        cH[mf] = *(const bf16x8*)(sAc + ((rowb[mf] + kh) ^ swr[mf]));
      __builtin_amdgcn_s_setprio(1);
      #pragma unroll
      for (int mf = 0; mf < 4; ++mf) {
        acc[mf][0] = __builtin_amdgcn_mfma_f32_16x16x32_bf16(cH[mf], b0, acc[mf][0], 0, 0, 0);
        acc[mf][1] = __builtin_amdgcn_mfma_f32_16x16x32_bf16(cH[mf], b1, acc[mf][1], 0, 0, 0);
        acc[mf][2] = __builtin_amdgcn_mfma_f32_16x16x32_bf16(cH[mf], b2, acc[mf][2], 0, 0, 0);
        acc[mf][3] = __builtin_amdgcn_mfma_f32_16x16x32_bf16(cH[mf], b3, acc[mf][3], 0, 0, 0);
      }
      __builtin_amdgcn_s_setprio(0);
      if (tb < 7) { b0 = n0; b1 = n1; b2 = n2; b3 = n3; }
      __builtin_amdgcn_sched_barrier(0);
    }

    // ---- epilogue: complete dist for this class, per row; running min
    #pragma unroll
    for (int mf = 0; mf < 4; ++mf) {
      float ps0 = 0.f, ps1 = 0.f, ps2 = 0.f, ps3 = 0.f;
      #pragma unroll
      for (int nf = 0; nf < 4; ++nf) {
        float gg = gv[nf];
        float t0 = acc[mf][nf][0] - gg; ps0 = fmaf(t0, t0, ps0);
        float t1 = acc[mf][nf][1] - gg; ps1 = fmaf(t1, t1, ps1);
        float t2 = acc[mf][nf][2] - gg; ps2 = fmaf(t2, t2, ps2);
        float t3 = acc[mf][nf][3] - gg; ps3 = fmaf(t3, t3, ps3);
      }
      #pragma unroll
      for (int off = 1; off < 16; off <<= 1) {
        ps0 += __shfl_xor(ps0, off);
        ps1 += __shfl_xor(ps1, off);
        ps2 += __shfl_xor(ps2, off);
        ps3 += __shfl_xor(ps3, off);
      }
      dmin[mf][0] = fminf(dmin[mf][0], ps0);
      dmin[mf][1] = fminf(dmin[mf][1], ps1);
      dmin[mf][2] = fminf(dmin[mf][2], ps2);
      dmin[mf][3] = fminf(dmin[mf][3], ps3);
    }
  }

  // ---- combine the 4 class-slot waves per row-half
  if (l15 == 0) {
    #pragma unroll
    for (int mf = 0; mf < 4; ++mf)
      #pragma unroll
      for (int r = 0; r < 4; ++r) {
        int row = mh * 64 + mf * 16 + (lane >> 4) * 4 + r;
        atomicMin(&sMin[row], __float_as_uint(dmin[mf][r]));
      }
  }
  __syncthreads();
  if (tid < MT) out[pxbase + tid] = __uint_as_float(sMin[tid]);
}

extern "C" void kernel_launch(void* const* d_in, const int* in_sizes, int n_in,
                              void* d_out, int out_size, void* d_ws, size_t ws_size,
                              hipStream_t stream) {
  const float* feats    = (const float*)d_in[0];
  const float* pca_mean = (const float*)d_in[1];
  const float* comps    = (const float*)d_in[2];
  const float* var      = (const float*)d_in[3];
  const float* mu       = (const float*)d_in[4];
  const float* cov_inv  = (const float*)d_in[5];
  float* out = (float*)d_out;

  // workspace (floats): rv[950] Lmat[47500] g[1280] Bs(bf16)[655360]
  float* w_rv = (float*)d_ws;
  float* Lmat = w_rv + Cc * Kk;
  float* gv   = Lmat + Cc * Kk * Kk;
  unsigned short* Bs = (unsigned short*)(gv + ROWS);

  const int n = in_sizes[0] / Dd;  // 131072 pixels

  prepchol_kernel<<<Cc, 256, 0, stream>>>(pca_mean, comps, var, mu, cov_inv,
                                          w_rv, Lmat, gv);
  prepB_kernel<<<ROWS, 256, 0, stream>>>(comps, w_rv, Lmat, gv, Bs);
  mfma_kernel<<<n / MT, THR, 0, stream>>>(feats, Bs, gv, out);
}